// Round 1
// 123.127 us; speedup vs baseline: 1.0001x; 1.0001x over previous
//
#include <hip/hip_runtime.h>
#include <hip/hip_bf16.h>
#include <math.h>

// DiscretisedBNF loss, MI355X gfx950.
// R14: pipelined gemm_k (T3-minimum 2-phase). Double-buffered LDS (45 KB), ONE raw
//      s_barrier per K-step (was 2x __syncthreads), tile k+1 global loads issued
//      pre-barrier and ds_written post-barrier (T14 async split) so HBM latency of
//      the once-read f32 W hides under ds_read+MFMA. lgkmcnt(0)+sched_barrier(0)
//      fence per guide rules #18/#21; accumulation order unchanged -> bit-identical.
// Structure: prep(A1 bf16) -> GEMM1(splitK=8) -> reduce1(+out=0) -> GEMM2(splitK=8) -> loss.
// Abel summation (k=127 edge kept un-saturated):
//   pO = (125/256)(1+erf(z_127)) - 126/128 - (1/128) sum_{k=1..126} erf(z_k),
//   z_k = (k/64 - 1 - mu_x) / (sigma*sqrt(2)).
// Interior sum via Euler-Maclaurin midpoint (O(1)); a>1 -> direct sum (<=7 terms).
// Session ledger: coop grid.sync ~60us/sync (R11); prep-in-gemm fusion costs 128MB
// redundant reads (R9); atomics regress (R12); BN=32@2blk/CU -3us (R6); loss O(1) -3us (R8).

typedef __bf16 bf16_t;
typedef __bf16 bf16x8 __attribute__((ext_vector_type(8)));
typedef __bf16 bf16x4 __attribute__((ext_vector_type(4)));
typedef float  f32x4  __attribute__((ext_vector_type(4)));

#define LDK 40  // LDS row stride in bf16 (32 + 8 pad): 80B rows, 16B-aligned
#define L2S -5.6438561897747248f  // log2(0.02)

// Abramowitz-Stegun 7.1.26, |abs err| <= 1.5e-7, branch-free full-range.
__device__ __forceinline__ float erf_f(float x) {
  float ax = __builtin_fabsf(x);
  float t = __builtin_amdgcn_rcpf(fmaf(0.3275911f, ax, 1.0f));
  float p = fmaf(fmaf(fmaf(fmaf(1.061405429f, t, -1.453152027f), t, 1.421413741f),
                      t, -0.284496736f), t, 0.254829592f);
  p *= t;
  float e = __expf(-ax * ax);
  float r = fmaf(-p, e, 1.0f);
  return __builtin_copysignf(r, x);
}

// block b handles row b (1024 elems, 256 thr x 4): A1 = gamma*x + gamma*(1-gamma)*noise, bf16.
__global__ __launch_bounds__(256, 2)
void prep_k(const float* __restrict__ x, const float* __restrict__ noise,
            const float* __restrict__ t, bf16_t* __restrict__ A1) {
  int b = blockIdx.x;
  float tv = t[b];
  float p = exp2f(2.0f * tv * L2S);        // 1-gamma = 0.02^(2t)
  float g = 1.0f - p, gom = g * p;         // gamma, gamma*(1-gamma)
  int e = (b * 256 + threadIdx.x) * 4;
  float4 xv = *(const float4*)(x + e);
  float4 nv = *(const float4*)(noise + e);
  bf16x4 o;
  o[0] = (__bf16)fmaf(gom, nv.x, g * xv.x);
  o[1] = (__bf16)fmaf(gom, nv.y, g * xv.y);
  o[2] = (__bf16)fmaf(gom, nv.z, g * xv.z);
  o[3] = (__bf16)fmaf(gom, nv.w, g * xv.w);
  *(bf16x4*)(A1 + e) = o;
}

// P[z] = A[256 x Kchunk, bf16] @ W[Kchunk x N, f32->bf16].
// BM=256, BN=32, BK=32. 4 waves, each 64(m)x32(n) = 4x2 frags of 16x16x32. [R6-proven]
// R14: 2-phase pipeline. Per K-step: write staged regs to LDS buf[cur], issue next
// tile's global loads, lgkmcnt(0)+s_barrier (ONE barrier), ds_read+8xMFMA.
// Single-barrier safety: DS ops complete in-order per wave, so the explicit
// lgkmcnt(0) before barrier k+1 also retires all of read-phase k's ds_reads ->
// no wave can see write k+2 touch buf[cur] before every read of it finished.
__global__ __launch_bounds__(256, 2)
void gemm_k(const bf16_t* __restrict__ A, int lda,
            const float* __restrict__ W, int N,
            float* __restrict__ P, int Ktiles, int Kchunk) {
  __shared__ bf16_t As[2][256 * LDK];
  __shared__ bf16_t Bs[2][32 * LDK];
  int tid = threadIdx.x;
  int lane = tid & 63, wave = tid >> 6;
  int n0 = blockIdx.x * 32;
  int k0 = blockIdx.z * Kchunk;
  int bn = tid & 31, bkg = tid >> 5;   // B staging: n (0..31), k-group of 4 (0..7)
  int fm = lane & 15, kq = lane >> 4;  // fragment lane decode

  const bf16_t* Arow = A + (size_t)tid * lda + k0;        // thread = row, 32-col chunk
  const float*  Wcol = W + (size_t)(k0 + bkg * 4) * N + n0 + bn;

  f32x4 acc[4][2];
#pragma unroll
  for (int i = 0; i < 4; ++i)
#pragma unroll
    for (int j = 0; j < 2; ++j) acc[i][j] = (f32x4)0.0f;

  // in-flight tile registers
  bf16x8 aR[4];
  float  bR[4];
  // prologue: load tile 0
#pragma unroll
  for (int j = 0; j < 4; ++j) aR[j] = *(const bf16x8*)(Arow + j * 8);
#pragma unroll
  for (int i = 0; i < 4; ++i) bR[i] = Wcol[(size_t)i * N];

  for (int kt = 0; kt < Ktiles; ++kt) {
    int cur = kt & 1;
    bf16_t* as = &As[cur][0];
    bf16_t* bs = &Bs[cur][0];
    // write staged tile kt to LDS (compiler inserts vmcnt wait on aR/bR here)
#pragma unroll
    for (int j = 0; j < 4; ++j)
      *(bf16x8*)(&as[tid * LDK + j * 8]) = aR[j];
    {
      bf16x4 bv;
#pragma unroll
      for (int i = 0; i < 4; ++i) bv[i] = (__bf16)bR[i];
      *(bf16x4*)(&bs[bn * LDK + bkg * 4]) = bv;
    }
    // issue tile kt+1 global loads; they stay in flight across the barrier and
    // are only vmcnt-waited at the top of the next iteration's LDS write.
    if (kt + 1 < Ktiles) {
      const bf16_t* Ar = Arow + (kt + 1) * 32;
#pragma unroll
      for (int j = 0; j < 4; ++j) aR[j] = *(const bf16x8*)(Ar + j * 8);
      const float* Wp = Wcol + (size_t)(kt + 1) * 32 * N;
#pragma unroll
      for (int i = 0; i < 4; ++i) bR[i] = Wp[(size_t)i * N];
    }
    // ds_writes complete (and, by DS in-order retire, all prior ds_reads too)
    asm volatile("s_waitcnt lgkmcnt(0)" ::: "memory");
    __builtin_amdgcn_s_barrier();
    __builtin_amdgcn_sched_barrier(0);  // nothing crosses the barrier (rule #18)

    bf16x8 aF[4], bF[2];
#pragma unroll
    for (int i = 0; i < 4; ++i)
      aF[i] = *(const bf16x8*)(&as[(wave * 64 + i * 16 + fm) * LDK + kq * 8]);
#pragma unroll
    for (int j = 0; j < 2; ++j)
      bF[j] = *(const bf16x8*)(&bs[(j * 16 + fm) * LDK + kq * 8]);
#pragma unroll
    for (int i = 0; i < 4; ++i)
#pragma unroll
      for (int j = 0; j < 2; ++j)
        acc[i][j] = __builtin_amdgcn_mfma_f32_16x16x32_bf16(aF[i], bF[j], acc[i][j], 0, 0, 0);
    // no second barrier: next iteration writes buf[cur^1], which nobody reads now.
  }
  // epilogue: C/D layout col=lane&15, row=(lane>>4)*4+reg  [m89-verified]
  float* Pp = P + (size_t)blockIdx.z * 256 * N + n0;
#pragma unroll
  for (int i = 0; i < 4; ++i) {
    int mrow = wave * 64 + i * 16 + kq * 4;
#pragma unroll
    for (int j = 0; j < 2; ++j)
#pragma unroll
      for (int r = 0; r < 4; ++r)
        Pp[(size_t)(mrow + r) * N + j * 16 + fm] = acc[i][j][r];
  }
}

// h = leaky(sum_s P1[s] + t*W1[1024,:] + b1), stored bf16. Block 0 also zeroes out.
__global__ __launch_bounds__(256, 2)
void reduce1_k(const float* __restrict__ P1, const float* __restrict__ W1,
               const float* __restrict__ b1, const float* __restrict__ t,
               bf16_t* __restrict__ h, float* __restrict__ out) {
  if (blockIdx.x == 0 && threadIdx.x == 0) *out = 0.0f;  // consumed 2 dispatches later
  int e = (blockIdx.x * 256 + threadIdx.x) * 4;
  int b = e >> 11, n = e & 2047;
  float4 s = *(const float4*)(P1 + e);
#pragma unroll
  for (int sp = 1; sp < 8; ++sp) {
    float4 v = *(const float4*)(P1 + (size_t)sp * 524288 + e);
    s.x += v.x; s.y += v.y; s.z += v.z; s.w += v.w;
  }
  float tv = t[b];
  float4 wl = *(const float4*)(W1 + 1024 * 2048 + n);
  float4 bb = *(const float4*)(b1 + n);
  s.x += tv * wl.x + bb.x;
  s.y += tv * wl.y + bb.y;
  s.z += tv * wl.z + bb.z;
  s.w += tv * wl.w + bb.w;
  bf16x4 o;
  o[0] = (__bf16)(s.x >= 0.f ? s.x : 0.01f * s.x);
  o[1] = (__bf16)(s.y >= 0.f ? s.y : 0.01f * s.y);
  o[2] = (__bf16)(s.z >= 0.f ? s.z : 0.01f * s.z);
  o[3] = (__bf16)(s.w >= 0.f ? s.w : 0.01f * s.w);
  *(bf16x4*)(h + e) = o;
}

// one thread per element; row consts inline from t; reduce GEMM2 partials,
// analytic erf bucket sum, weighted MSE.
__global__ __launch_bounds__(256, 4)
void loss_k(const float* __restrict__ x, const float* __restrict__ noise,
            const float* __restrict__ P2, const float* __restrict__ b2,
            const float* __restrict__ t, float* __restrict__ out) {
  int gid = blockIdx.x * 256 + threadIdx.x;  // 0..262143
  int b = gid >> 10, d = gid & 1023;
  float tv = t[b];
  float om = exp2f(2.0f * tv * L2S);         // 1-gamma
  float gamma = 1.0f - om;
  float r = sqrtf(om / gamma);
  float w = 1.0f / om;                       // SIGMA1^(-2t)
  bool lowt = tv < 1e-10f;
  int base2 = b * 2048 + d;
  float me = b2[d], lg = b2[1024 + d];
#pragma unroll
  for (int sp = 0; sp < 8; ++sp) {
    me += P2[(size_t)sp * 524288 + base2];
    lg += P2[(size_t)sp * 524288 + base2 + 1024];
  }
  float xs = x[gid], ns = noise[gid];

  float mu_x = xs + om * ns - r * me;        // mu/gamma - r*mu_eps
  float sig = r * __expf(lg);
  if (lowt) { mu_x = 0.f; sig = 1.f; }
  float invs = 0.70710678118654752f / sig;   // 1/(sigma*sqrt(2))
  float a = invs * 0.015625f;                // z step per k
  float c0 = (1.f + mu_x) * invs;            // z_k = a*k - c0
  // window |z|<3.5 for the k=1..126 interior sum; saturated tails counted exactly
  float m64 = 64.f * (1.f + mu_x);
  float wdt = 316.78383797157331f * sig;     // 3.5/a = 224*sqrt(2)*sig
  float lo = m64 - wdt, hi = m64 + wdt;
  int klo = (lo < 1.f) ? 1 : ((lo > 126.f) ? 127 : (int)ceilf(lo));
  int khi = (hi < 1.f) ? 0 : ((hi > 126.f) ? 126 : (int)floorf(hi));
  float ss = (float)(126 - khi) - (float)(klo - 1);  // erf=+1 above window, -1 below
  if (khi >= klo) {
    if (a <= 1.0f) {
      // Euler-Maclaurin midpoint: sum ~ (1/a)[G(zb)-G(za)] - (a/(12 sqrt(pi)))(eb-ea)
      float za = fmaf(a, (float)klo - 0.5f, -c0);
      float zb = fmaf(a, (float)khi + 0.5f, -c0);
      const float ISP = 0.56418958354775628f;  // 1/sqrt(pi)
      float ea = __expf(-za * za), eb = __expf(-zb * zb);
      float Ga = fmaf(za, erf_f(za), ISP * ea); // G(z)=z*erf(z)+e^{-z^2}/sqrt(pi), G'=erf
      float Gb = fmaf(zb, erf_f(zb), ISP * eb);
      float S = (Gb - Ga) * __builtin_amdgcn_rcpf(a)
              - a * 0.047015889f * (eb - ea);   // 1/(12*sqrt(pi))
      ss += S;
    } else {
      for (int k = klo; k <= khi; ++k) ss += erf_f(fmaf(a, (float)k, -c0));
    }
  }
  // non-saturated right edge term at k=127 (kr_127 = 63/64 < 1, not clamped)
  float z127 = fmaf(a, 127.f, -c0);
  float pO = fmaf(0.48828125f, 1.f + erf_f(z127),      // (125/256)(1+erf(z127))
                  fmaf(-0.0078125f, ss, -0.984375f));  // -(1/128)ss - 126/128
  float df = xs - pO;
  float accv = w * df * df;
#pragma unroll
  for (int off = 32; off > 0; off >>= 1) accv += __shfl_down(accv, off, 64);
  __shared__ float red[4];
  if ((threadIdx.x & 63) == 0) red[threadIdx.x >> 6] = accv;
  __syncthreads();
  if (threadIdx.x == 0) {
    const float SCALE = 3.9120230054281461f / 262144.0f;  // -ln(0.02)/(B*D)
    atomicAdd(out, (red[0] + red[1] + red[2] + red[3]) * SCALE);
  }
}

extern "C" void kernel_launch(void* const* d_in, const int* in_sizes, int n_in,
                              void* d_out, int out_size, void* d_ws, size_t ws_size,
                              hipStream_t stream) {
  const float* x     = (const float*)d_in[0];
  const float* t     = (const float*)d_in[1];
  const float* noise = (const float*)d_in[2];
  const float* W1    = (const float*)d_in[3];
  const float* b1    = (const float*)d_in[4];
  const float* W2    = (const float*)d_in[5];
  const float* b2    = (const float*)d_in[6];
  float* out = (float*)d_out;

  // ws layout (needs ~34 MB)
  char* ws = (char*)d_ws;
  bf16_t* A1 = (bf16_t*)ws;                        // 512 KB
  bf16_t* h  = (bf16_t*)(ws + 524288);             // 1 MB
  float*  P1 = (float*)(ws + 524288 + 1048576);    // 16 MB
  float*  P2 = (float*)(ws + 524288 + 1048576 + 16777216);  // 16 MB

  prep_k<<<256, 256, 0, stream>>>(x, noise, t, A1);
  gemm_k<<<dim3(64, 1, 8), 256, 0, stream>>>(A1, 1024, W1, 2048, P1, 4, 128);
  reduce1_k<<<512, 256, 0, stream>>>(P1, W1, b1, t, h, out);
  gemm_k<<<dim3(64, 1, 8), 256, 0, stream>>>(h, 2048, W2, 2048, P2, 8, 256);
  loss_k<<<1024, 256, 0, stream>>>(x, noise, P2, b2, t, out);
}

// Round 2
// 112.351 us; speedup vs baseline: 1.0960x; 1.0959x over previous
//
#include <hip/hip_runtime.h>
#include <hip/hip_bf16.h>
#include <math.h>

// DiscretisedBNF loss, MI355X gfx950.
// R15: structural fusion, 5 -> 3 dispatches. Theory: R14's pipeline was exactly
//      neutral => GEMM inner loops are NOT the cost; per-dispatch boundaries +
//      splitK partial round-trips are. Changes:
//      - no splitK: BM=64 x BN=32 -> grid 4x64 = 256 blocks = 1/CU, full K per block.
//        P1/P2 partial buffers (64 MB round-trip) deleted.
//      - reduce1_k deleted: bias + t*W1[1024,:] + leaky fused into gemm1 epilogue.
//      - loss fused into gemm2 epilogue: block's 32 W2-cols = {d..d+15} u {1024+d..},
//        so each thread holds (mu_eps, ln_sig_eps) pairs; erf/E-M loss in-register,
//        one atomicAdd per block. out zeroed in prep_k.
//      - depth-4 register prefetch ring (named regs, static idx) over the R14
//        single-barrier LDS double-buffer: covers HBM latency of the serial K-chain.
//      - W-panel L2 reuse: m-blocks sharing a W panel are 64 apart in linear block
//        id => same XCD (id%8), so W1/W2 re-reads hit that XCD's L2.
// Abel summation (k=127 edge kept un-saturated):
//   pO = (125/256)(1+erf(z_127)) - 126/128 - (1/128) sum_{k=1..126} erf(z_k),
//   z_k = (k/64 - 1 - mu_x) / (sigma*sqrt(2)).
// Interior sum via Euler-Maclaurin midpoint (O(1)); a>1 -> direct sum (<=7 terms).
// Ledger: coop grid.sync ~60us/sync (R11); prep-in-gemm fusion costs 128MB redundant
// reads (R9 - prep stays separate); atomics on splitK partials regress (R12 - but
// 256 block-level loss atomics == old loss_k pattern); 2-phase pipeline neutral (R14).

typedef __bf16 bf16_t;
typedef __bf16 bf16x8 __attribute__((ext_vector_type(8)));
typedef __bf16 bf16x4 __attribute__((ext_vector_type(4)));
typedef float  f32x4  __attribute__((ext_vector_type(4)));

#define LDK 40  // LDS row stride in bf16 (32 + 8 pad): 80B rows, 16B-aligned
#define L2S -5.6438561897747248f  // log2(0.02)

// Abramowitz-Stegun 7.1.26, |abs err| <= 1.5e-7, branch-free full-range.
__device__ __forceinline__ float erf_f(float x) {
  float ax = __builtin_fabsf(x);
  float t = __builtin_amdgcn_rcpf(fmaf(0.3275911f, ax, 1.0f));
  float p = fmaf(fmaf(fmaf(fmaf(1.061405429f, t, -1.453152027f), t, 1.421413741f),
                      t, -0.284496736f), t, 0.254829592f);
  p *= t;
  float e = __expf(-ax * ax);
  float r = fmaf(-p, e, 1.0f);
  return __builtin_copysignf(r, x);
}

// block b handles row b (1024 elems, 256 thr x 4): A1 = gamma*x + gamma*(1-gamma)*noise.
// Also zeroes the loss accumulator (consumed 2 dispatches later by gemm2loss_k).
__global__ __launch_bounds__(256, 2)
void prep_k(const float* __restrict__ x, const float* __restrict__ noise,
            const float* __restrict__ t, bf16_t* __restrict__ A1,
            float* __restrict__ out) {
  if (blockIdx.x == 0 && threadIdx.x == 0) *out = 0.0f;
  int b = blockIdx.x;
  float tv = t[b];
  float p = exp2f(2.0f * tv * L2S);        // 1-gamma = 0.02^(2t)
  float g = 1.0f - p, gom = g * p;         // gamma, gamma*(1-gamma)
  int e = (b * 256 + threadIdx.x) * 4;
  float4 xv = *(const float4*)(x + e);
  float4 nv = *(const float4*)(noise + e);
  bf16x4 o;
  o[0] = (__bf16)fmaf(gom, nv.x, g * xv.x);
  o[1] = (__bf16)fmaf(gom, nv.y, g * xv.y);
  o[2] = (__bf16)fmaf(gom, nv.z, g * xv.z);
  o[3] = (__bf16)fmaf(gom, nv.w, g * xv.w);
  *(bf16x4*)(A1 + e) = o;
}

// ---- shared GEMM inner loop ----------------------------------------------
// BM=64 (4 waves x 16 rows), BN=32 logical cols, BK=32, N(row stride of W)=2048.
// Depth-4 register ring (aR0..3 / bR0..3, statically indexed) over a 2-buffer LDS
// pipeline; ONE raw s_barrier per K-step (R14 structure, safety proof unchanged:
// DS ops retire in-order per wave, so lgkmcnt(0) before barrier k+1 retires phase
// k's ds_reads; buffer[cur] is only rewritten at k+2, after barrier k+1).
// Compiler emits counted vmcnt (~T4): ds_write of tile k waits only for loads
// issued 4 phases earlier; tiles k+1..k+4 stay in flight across barriers.
#define GSTEP(ASB, BSB, AR, BR, TILE, PF)                                        \
  {                                                                              \
    *(bf16x8*)(&ASB[arow * LDK + akg * 8]) = AR;                                 \
    bf16x4 bv_;                                                                  \
    bv_[0] = (__bf16)BR[0]; bv_[1] = (__bf16)BR[1];                              \
    bv_[2] = (__bf16)BR[2]; bv_[3] = (__bf16)BR[3];                              \
    *(bf16x4*)(&BSB[bn * LDK + bkg * 4]) = bv_;                                  \
    if (PF) {                                                                    \
      AR = *(const bf16x8*)(Ap + ((TILE) + 4) * 32);                             \
      const float* wp_ = Wp0 + (size_t)((TILE) + 4) * 32 * 2048;                 \
      BR[0] = wp_[0]; BR[1] = wp_[2048]; BR[2] = wp_[4096]; BR[3] = wp_[6144];   \
    }                                                                            \
    asm volatile("s_waitcnt lgkmcnt(0)" ::: "memory");                           \
    __builtin_amdgcn_s_barrier();                                                \
    __builtin_amdgcn_sched_barrier(0);                                           \
    {                                                                            \
      bf16x8 aF_ = *(const bf16x8*)(&ASB[(wave * 16 + fm) * LDK + kq * 8]);      \
      bf16x8 bF0_ = *(const bf16x8*)(&BSB[fm * LDK + kq * 8]);                   \
      bf16x8 bF1_ = *(const bf16x8*)(&BSB[(16 + fm) * LDK + kq * 8]);            \
      acc0 = __builtin_amdgcn_mfma_f32_16x16x32_bf16(aF_, bF0_, acc0, 0, 0, 0);  \
      acc1 = __builtin_amdgcn_mfma_f32_16x16x32_bf16(aF_, bF1_, acc1, 0, 0, 0);  \
    }                                                                            \
  }

__device__ __forceinline__ void gemm_loop(
    const bf16_t* __restrict__ Ap, const float* __restrict__ Wp0,
    bf16_t* __restrict__ As0, bf16_t* __restrict__ As1,
    bf16_t* __restrict__ Bs0, bf16_t* __restrict__ Bs1,
    int arow, int akg, int bn, int bkg, int wave, int fm, int kq,
    int Ktiles, f32x4& acc0, f32x4& acc1) {
  bf16x8 aR0, aR1, aR2, aR3;
  f32x4 bR0, bR1, bR2, bR3;
  // prologue: tiles 0..3 in flight (Ktiles is 32 or 64, always >= 4)
  aR0 = *(const bf16x8*)(Ap);
  aR1 = *(const bf16x8*)(Ap + 32);
  aR2 = *(const bf16x8*)(Ap + 64);
  aR3 = *(const bf16x8*)(Ap + 96);
  {
    const float* w_ = Wp0;
    bR0[0] = w_[0]; bR0[1] = w_[2048]; bR0[2] = w_[4096]; bR0[3] = w_[6144];
    w_ = Wp0 + (size_t)32 * 2048;
    bR1[0] = w_[0]; bR1[1] = w_[2048]; bR1[2] = w_[4096]; bR1[3] = w_[6144];
    w_ = Wp0 + (size_t)64 * 2048;
    bR2[0] = w_[0]; bR2[1] = w_[2048]; bR2[2] = w_[4096]; bR2[3] = w_[6144];
    w_ = Wp0 + (size_t)96 * 2048;
    bR3[0] = w_[0]; bR3[1] = w_[2048]; bR3[2] = w_[4096]; bR3[3] = w_[6144];
  }
  for (int kt = 0; kt < Ktiles; kt += 4) {
    GSTEP(As0, Bs0, aR0, bR0, kt,     kt + 4 < Ktiles)
    GSTEP(As1, Bs1, aR1, bR1, kt + 1, kt + 5 < Ktiles)
    GSTEP(As0, Bs0, aR2, bR2, kt + 2, kt + 6 < Ktiles)
    GSTEP(As1, Bs1, aR3, bR3, kt + 3, kt + 7 < Ktiles)
  }
}

// h = leaky(A1 @ W1[0:1024,:] + t*W1[1024,:] + b1), bf16.
// grid (64 n, 4 m); block: 64 rows x 32 cols, K=1024 (Ktiles=32).
__global__ __launch_bounds__(256, 2)
void gemm1h_k(const bf16_t* __restrict__ A, const float* __restrict__ W,
              const float* __restrict__ b1, const float* __restrict__ t,
              bf16_t* __restrict__ h) {
  __shared__ bf16_t As0[64 * LDK], As1[64 * LDK];
  __shared__ bf16_t Bs0[32 * LDK], Bs1[32 * LDK];
  int tid = threadIdx.x;
  int lane = tid & 63, wave = tid >> 6;
  int n0 = blockIdx.x * 32, m0 = blockIdx.y * 64;
  int arow = tid >> 2, akg = tid & 3;   // A staging: row (0..63), k-group of 8
  int bn = tid & 31, bkg = tid >> 5;    // B staging: col (0..31), k-group of 4
  int fm = lane & 15, kq = lane >> 4;   // fragment lane decode

  const bf16_t* Ap = A + (size_t)(m0 + arow) * 1024 + akg * 8;
  const float* Wp0 = W + (size_t)(bkg * 4) * 2048 + n0 + bn;

  f32x4 acc0 = (f32x4)0.0f, acc1 = (f32x4)0.0f;
  gemm_loop(Ap, Wp0, As0, As1, Bs0, Bs1, arow, akg, bn, bkg, wave, fm, kq,
            32, acc0, acc1);

  // epilogue: C/D layout col=lane&15, row=(lane>>4)*4+reg [m89-verified]
  int col0 = n0 + fm, col1 = n0 + 16 + fm;
  float wl0 = W[(size_t)1024 * 2048 + col0], wl1 = W[(size_t)1024 * 2048 + col1];
  float bb0 = b1[col0], bb1 = b1[col1];
#pragma unroll
  for (int e = 0; e < 4; ++e) {
    int row = m0 + wave * 16 + kq * 4 + e;
    float tv = t[row];
    float v0 = acc0[e] + tv * wl0 + bb0;
    float v1 = acc1[e] + tv * wl1 + bb1;
    v0 = v0 >= 0.f ? v0 : 0.01f * v0;
    v1 = v1 >= 0.f ? v1 : 0.01f * v1;
    h[(size_t)row * 2048 + col0] = (__bf16)v0;
    h[(size_t)row * 2048 + col1] = (__bf16)v1;
  }
}

// out2 = h @ W2 + b2, with cols {d..d+15} u {1024+d..1024+d+15} per block so each
// thread holds (mu_eps, ln_sig_eps) pairs; loss computed in-register, one
// atomicAdd per block. grid (64 n, 4 m); block 64 rows x (16+16) cols, K=2048.
__global__ __launch_bounds__(256, 2)
void gemm2loss_k(const bf16_t* __restrict__ A, const float* __restrict__ W,
                 const float* __restrict__ b2, const float* __restrict__ t,
                 const float* __restrict__ x, const float* __restrict__ noise,
                 float* __restrict__ out) {
  __shared__ bf16_t As0[64 * LDK], As1[64 * LDK];
  __shared__ bf16_t Bs0[32 * LDK], Bs1[32 * LDK];
  __shared__ float red[4];
  int tid = threadIdx.x;
  int lane = tid & 63, wave = tid >> 6;
  int n0 = blockIdx.x * 16, m0 = blockIdx.y * 64;
  int arow = tid >> 2, akg = tid & 3;
  int bn = tid & 31, bkg = tid >> 5;
  int fm = lane & 15, kq = lane >> 4;

  const bf16_t* Ap = A + (size_t)(m0 + arow) * 2048 + akg * 8;
  // dual-panel column map: bn 0..15 -> me cols n0+bn, bn 16..31 -> lg cols 1024+n0+bn-16
  int bcol = n0 + (bn & 15) + ((bn >> 4) << 10);
  const float* Wp0 = W + (size_t)(bkg * 4) * 2048 + bcol;

  f32x4 acc0 = (f32x4)0.0f, acc1 = (f32x4)0.0f;  // acc0 = mu_eps frag, acc1 = ln_sig frag
  gemm_loop(Ap, Wp0, As0, As1, Bs0, Bs1, arow, akg, bn, bkg, wave, fm, kq,
            64, acc0, acc1);

  // fused loss epilogue: 4 elements per thread (rows kq*4+e, col d=n0+fm)
  int d = n0 + fm;
  float bme = b2[d], blg = b2[1024 + d];
  float lsum = 0.0f;
#pragma unroll
  for (int e = 0; e < 4; ++e) {
    int row = m0 + wave * 16 + kq * 4 + e;
    float tv = t[row];
    float om = exp2f(2.0f * tv * L2S);       // 1-gamma
    float gamma = 1.0f - om;
    float rq = sqrtf(om / gamma);
    float w = 1.0f / om;                     // SIGMA1^(-2t)
    bool lowt = tv < 1e-10f;
    float me = acc0[e] + bme;
    float lg = acc1[e] + blg;
    float xs = x[(size_t)row * 1024 + d], ns = noise[(size_t)row * 1024 + d];

    float mu_x = xs + om * ns - rq * me;     // mu/gamma - r*mu_eps
    float sig = rq * __expf(lg);
    if (lowt) { mu_x = 0.f; sig = 1.f; }
    float invs = 0.70710678118654752f / sig; // 1/(sigma*sqrt(2))
    float a = invs * 0.015625f;              // z step per k
    float c0 = (1.f + mu_x) * invs;          // z_k = a*k - c0
    // window |z|<3.5 for the k=1..126 interior sum; saturated tails counted exactly
    float m64 = 64.f * (1.f + mu_x);
    float wdt = 316.78383797157331f * sig;   // 3.5/a = 224*sqrt(2)*sig
    float lo = m64 - wdt, hi = m64 + wdt;
    int klo = (lo < 1.f) ? 1 : ((lo > 126.f) ? 127 : (int)ceilf(lo));
    int khi = (hi < 1.f) ? 0 : ((hi > 126.f) ? 126 : (int)floorf(hi));
    float ss = (float)(126 - khi) - (float)(klo - 1);
    if (khi >= klo) {
      if (a <= 1.0f) {
        // Euler-Maclaurin midpoint: sum ~ (1/a)[G(zb)-G(za)] - (a/(12 sqrt(pi)))(eb-ea)
        float za = fmaf(a, (float)klo - 0.5f, -c0);
        float zb = fmaf(a, (float)khi + 0.5f, -c0);
        const float ISP = 0.56418958354775628f;  // 1/sqrt(pi)
        float ea = __expf(-za * za), eb = __expf(-zb * zb);
        float Ga = fmaf(za, erf_f(za), ISP * ea);
        float Gb = fmaf(zb, erf_f(zb), ISP * eb);
        float S = (Gb - Ga) * __builtin_amdgcn_rcpf(a)
                - a * 0.047015889f * (eb - ea);  // 1/(12*sqrt(pi))
        ss += S;
      } else {
        for (int k = klo; k <= khi; ++k) ss += erf_f(fmaf(a, (float)k, -c0));
      }
    }
    float z127 = fmaf(a, 127.f, -c0);
    float pO = fmaf(0.48828125f, 1.f + erf_f(z127),
                    fmaf(-0.0078125f, ss, -0.984375f));
    float df = xs - pO;
    lsum += w * df * df;
  }
#pragma unroll
  for (int off = 32; off > 0; off >>= 1) lsum += __shfl_down(lsum, off, 64);
  if ((tid & 63) == 0) red[wave] = lsum;
  __syncthreads();
  if (tid == 0) {
    const float SCALE = 3.9120230054281461f / 262144.0f;  // -ln(0.02)/(B*D)
    atomicAdd(out, (red[0] + red[1] + red[2] + red[3]) * SCALE);
  }
}

extern "C" void kernel_launch(void* const* d_in, const int* in_sizes, int n_in,
                              void* d_out, int out_size, void* d_ws, size_t ws_size,
                              hipStream_t stream) {
  const float* x     = (const float*)d_in[0];
  const float* t     = (const float*)d_in[1];
  const float* noise = (const float*)d_in[2];
  const float* W1    = (const float*)d_in[3];
  const float* b1    = (const float*)d_in[4];
  const float* W2    = (const float*)d_in[5];
  const float* b2    = (const float*)d_in[6];
  float* out = (float*)d_out;

  // ws layout (1.5 MB live): A1 bf16 512 KB, h bf16 1 MB
  char* ws = (char*)d_ws;
  bf16_t* A1 = (bf16_t*)ws;
  bf16_t* h  = (bf16_t*)(ws + 524288);

  prep_k<<<256, 256, 0, stream>>>(x, noise, t, A1, out);
  gemm1h_k<<<dim3(64, 4), 256, 0, stream>>>(A1, W1, b1, t, h);
  gemm2loss_k<<<dim3(64, 4), 256, 0, stream>>>(h, W2, b2, t, x, noise, out);
}

// Round 3
// 110.329 us; speedup vs baseline: 1.1161x; 1.0183x over previous
//
#include <hip/hip_runtime.h>
#include <hip/hip_bf16.h>
#include <math.h>

// DiscretisedBNF loss, MI355X gfx950.
// R16: attack the latency regime. R15's grid (64x4)=256 blocks = 1 block/CU =
//      1 wave/SIMD: every barrier-step's ds_write->barrier->ds_read(120cyc) chain
//      fully exposed, no co-resident wave to hide it. Changes:
//      - block tile 32x32 (4 waves as 2x2 of 16x16, ONE acc/wave) -> grid (64,8)
//        = 512 blocks = 2 blocks/CU = 2 waves/SIMD (barrier-stall of one block
//        hidden by the other).
//      - BK=64 (2 MFMA per step, same ascending-k chain => bit-identical):
//        gemm2 64->32 barrier-steps, gemm1 32->16.
//      - LDS stride 72 bf16 (36 dwords = 4*odd): optimal 8-lane/bank-cluster
//        spread for ds_read_b128 (same property as R15's proven LDK=40).
//      - gemm2 (me,lg) pairing now crosses waves (wc=0 holds mu_eps cols,
//        wc=1 holds ln_sig cols): 2KB LDS exchange in epilogue, loss on wc=0 half.
//      - depth-4 register prefetch ring kept (256 k ahead).
// Structure: prep(A1 bf16, zero out) -> gemm1+leaky(h) -> gemm2+loss.
// Abel summation (k=127 edge kept un-saturated):
//   pO = (125/256)(1+erf(z_127)) - 126/128 - (1/128) sum_{k=1..126} erf(z_k),
//   z_k = (k/64 - 1 - mu_x) / (sigma*sqrt(2)).
// Interior sum via Euler-Maclaurin midpoint (O(1)); a>1 -> direct sum (<=7 terms).
// Ledger: coop grid.sync ~60us (R11); prep-in-gemm fusion +128MB reads (R9);
// splitK atomics regress (R12); 2-phase pipeline alone neutral (R14); 5->3
// dispatch fusion -10.8us (R15). Harness poison-fill (268MB, ~42.7us) is fixed cost.

typedef __bf16 bf16_t;
typedef __bf16 bf16x8 __attribute__((ext_vector_type(8)));
typedef __bf16 bf16x4 __attribute__((ext_vector_type(4)));
typedef float  f32x4  __attribute__((ext_vector_type(4)));
typedef float  f32x8  __attribute__((ext_vector_type(8)));

#define LDK2 72  // LDS row stride in bf16 for BK=64 (64 + 8 pad) = 36 dwords
#define L2S -5.6438561897747248f  // log2(0.02)

// Abramowitz-Stegun 7.1.26, |abs err| <= 1.5e-7, branch-free full-range.
__device__ __forceinline__ float erf_f(float x) {
  float ax = __builtin_fabsf(x);
  float t = __builtin_amdgcn_rcpf(fmaf(0.3275911f, ax, 1.0f));
  float p = fmaf(fmaf(fmaf(fmaf(1.061405429f, t, -1.453152027f), t, 1.421413741f),
                      t, -0.284496736f), t, 0.254829592f);
  p *= t;
  float e = __expf(-ax * ax);
  float r = fmaf(-p, e, 1.0f);
  return __builtin_copysignf(r, x);
}

// block b handles row b (1024 elems, 256 thr x 4): A1 = gamma*x + gamma*(1-gamma)*noise.
// Also zeroes the loss accumulator (consumed 2 dispatches later by gemm2loss_k).
__global__ __launch_bounds__(256, 2)
void prep_k(const float* __restrict__ x, const float* __restrict__ noise,
            const float* __restrict__ t, bf16_t* __restrict__ A1,
            float* __restrict__ out) {
  if (blockIdx.x == 0 && threadIdx.x == 0) *out = 0.0f;
  int b = blockIdx.x;
  float tv = t[b];
  float p = exp2f(2.0f * tv * L2S);        // 1-gamma = 0.02^(2t)
  float g = 1.0f - p, gom = g * p;         // gamma, gamma*(1-gamma)
  int e = (b * 256 + threadIdx.x) * 4;
  float4 xv = *(const float4*)(x + e);
  float4 nv = *(const float4*)(noise + e);
  bf16x4 o;
  o[0] = (__bf16)fmaf(gom, nv.x, g * xv.x);
  o[1] = (__bf16)fmaf(gom, nv.y, g * xv.y);
  o[2] = (__bf16)fmaf(gom, nv.z, g * xv.z);
  o[3] = (__bf16)fmaf(gom, nv.w, g * xv.w);
  *(bf16x4*)(A1 + e) = o;
}

// ---- shared GEMM inner loop ----------------------------------------------
// Block tile 32(m) x 32(n virtual), BK=64, 4 waves as 2x2 of 16x16 frags.
// Depth-4 register ring over 2-buffer LDS; ONE raw s_barrier per K-step.
// Safety (unchanged from R14): DS ops retire in-order per wave, so the
// lgkmcnt(0) before barrier k+1 also retires phase k's ds_reads; buffer[cur]
// is only rewritten at k+2, after barrier k+1 -> no read-write race.
// A staging: thread = (row = tid>>3, 16B granule = tid&7)   [32x64 bf16 tile]
// B staging: thread = (col = tid&31, k-octet = tid>>5), 8 strided f32 -> bf16x8.
#define GSTEP(ASB, BSB, AR, BR, TILE, PF)                                        \
  {                                                                              \
    *(bf16x8*)(&ASB[arow * LDK2 + akg8]) = AR;                                   \
    bf16x8 bv_;                                                                  \
    bv_[0] = (__bf16)BR[0]; bv_[1] = (__bf16)BR[1];                              \
    bv_[2] = (__bf16)BR[2]; bv_[3] = (__bf16)BR[3];                              \
    bv_[4] = (__bf16)BR[4]; bv_[5] = (__bf16)BR[5];                              \
    bv_[6] = (__bf16)BR[6]; bv_[7] = (__bf16)BR[7];                              \
    *(bf16x8*)(&BSB[bn * LDK2 + bkg8]) = bv_;                                    \
    if (PF) {                                                                    \
      AR = *(const bf16x8*)(Ap + ((TILE) + 4) * 64);                             \
      const float* wp_ = Wp0 + (size_t)((TILE) + 4) * 64 * 2048;                 \
      BR[0] = wp_[0];        BR[1] = wp_[2048];                                  \
      BR[2] = wp_[4096];     BR[3] = wp_[6144];                                  \
      BR[4] = wp_[8192];     BR[5] = wp_[10240];                                 \
      BR[6] = wp_[12288];    BR[7] = wp_[14336];                                 \
    }                                                                            \
    asm volatile("s_waitcnt lgkmcnt(0)" ::: "memory");                           \
    __builtin_amdgcn_s_barrier();                                                \
    __builtin_amdgcn_sched_barrier(0);                                           \
    {                                                                            \
      bf16x8 aF0_ = *(const bf16x8*)(&ASB[arr]);                                 \
      bf16x8 bF0_ = *(const bf16x8*)(&BSB[brr]);                                 \
      acc = __builtin_amdgcn_mfma_f32_16x16x32_bf16(aF0_, bF0_, acc, 0, 0, 0);   \
      bf16x8 aF1_ = *(const bf16x8*)(&ASB[arr + 32]);                            \
      bf16x8 bF1_ = *(const bf16x8*)(&BSB[brr + 32]);                            \
      acc = __builtin_amdgcn_mfma_f32_16x16x32_bf16(aF1_, bF1_, acc, 0, 0, 0);   \
    }                                                                            \
  }

__device__ __forceinline__ void gemm_loop(
    const bf16_t* __restrict__ Ap, const float* __restrict__ Wp0,
    bf16_t* __restrict__ As0, bf16_t* __restrict__ As1,
    bf16_t* __restrict__ Bs0, bf16_t* __restrict__ Bs1,
    int arow, int akg8, int bn, int bkg8, int arr, int brr,
    int Ktiles, f32x4& acc) {
  bf16x8 aR0, aR1, aR2, aR3;
  f32x8 bR0, bR1, bR2, bR3;
  // prologue: tiles 0..3 in flight (Ktiles is 16 or 32, always >= 4)
  aR0 = *(const bf16x8*)(Ap);
  aR1 = *(const bf16x8*)(Ap + 64);
  aR2 = *(const bf16x8*)(Ap + 128);
  aR3 = *(const bf16x8*)(Ap + 192);
  {
    const float* w_ = Wp0;
    bR0[0] = w_[0];     bR0[1] = w_[2048];  bR0[2] = w_[4096];  bR0[3] = w_[6144];
    bR0[4] = w_[8192];  bR0[5] = w_[10240]; bR0[6] = w_[12288]; bR0[7] = w_[14336];
    w_ = Wp0 + (size_t)64 * 2048;
    bR1[0] = w_[0];     bR1[1] = w_[2048];  bR1[2] = w_[4096];  bR1[3] = w_[6144];
    bR1[4] = w_[8192];  bR1[5] = w_[10240]; bR1[6] = w_[12288]; bR1[7] = w_[14336];
    w_ = Wp0 + (size_t)128 * 2048;
    bR2[0] = w_[0];     bR2[1] = w_[2048];  bR2[2] = w_[4096];  bR2[3] = w_[6144];
    bR2[4] = w_[8192];  bR2[5] = w_[10240]; bR2[6] = w_[12288]; bR2[7] = w_[14336];
    w_ = Wp0 + (size_t)192 * 2048;
    bR3[0] = w_[0];     bR3[1] = w_[2048];  bR3[2] = w_[4096];  bR3[3] = w_[6144];
    bR3[4] = w_[8192];  bR3[5] = w_[10240]; bR3[6] = w_[12288]; bR3[7] = w_[14336];
  }
  for (int kt = 0; kt < Ktiles; kt += 4) {
    GSTEP(As0, Bs0, aR0, bR0, kt,     kt + 4 < Ktiles)
    GSTEP(As1, Bs1, aR1, bR1, kt + 1, kt + 5 < Ktiles)
    GSTEP(As0, Bs0, aR2, bR2, kt + 2, kt + 6 < Ktiles)
    GSTEP(As1, Bs1, aR3, bR3, kt + 3, kt + 7 < Ktiles)
  }
}

// h = leaky(A1 @ W1[0:1024,:] + t*W1[1024,:] + b1), bf16.
// grid (64 n, 8 m) = 512 blocks; block: 32 rows x 32 cols, K=1024 (16 tiles of 64).
__global__ __launch_bounds__(256, 2)
void gemm1h_k(const bf16_t* __restrict__ A, const float* __restrict__ W,
              const float* __restrict__ b1, const float* __restrict__ t,
              bf16_t* __restrict__ h) {
  __shared__ bf16_t As0[32 * LDK2], As1[32 * LDK2];
  __shared__ bf16_t Bs0[32 * LDK2], Bs1[32 * LDK2];
  int tid = threadIdx.x;
  int lane = tid & 63, wave = tid >> 6;
  int wr = wave & 1, wc = wave >> 1;    // 2x2 wave grid: rows wr*16, cols wc*16
  int n0 = blockIdx.x * 32, m0 = blockIdx.y * 32;
  int arow = tid >> 3, akg8 = (tid & 7) * 8;  // A staging: row, 16B granule
  int bn = tid & 31, bkg8 = (tid >> 5) * 8;   // B staging: col, k-octet
  int fm = lane & 15, kq = lane >> 4;         // fragment lane decode
  int arr = (wr * 16 + fm) * LDK2 + kq * 8;
  int brr = (wc * 16 + fm) * LDK2 + kq * 8;

  const bf16_t* Ap = A + (size_t)(m0 + arow) * 1024 + akg8;
  const float* Wp0 = W + (size_t)(bkg8 >> 3) * 8 * 2048 + n0 + bn;

  f32x4 acc = (f32x4)0.0f;
  gemm_loop(Ap, Wp0, As0, As1, Bs0, Bs1, arow, akg8, bn, bkg8, arr, brr,
            16, acc);

  // epilogue: C/D layout col=lane&15, row=(lane>>4)*4+reg [m89-verified]
  int col = n0 + wc * 16 + fm;
  float wl = W[(size_t)1024 * 2048 + col];
  float bb = b1[col];
#pragma unroll
  for (int e = 0; e < 4; ++e) {
    int row = m0 + wr * 16 + kq * 4 + e;
    float tv = t[row];
    float v = acc[e] + tv * wl + bb;
    v = v >= 0.f ? v : 0.01f * v;
    h[(size_t)row * 2048 + col] = (__bf16)v;
  }
}

// out2 = h @ W2 + b2 with virtual cols {d..d+15} u {1024+d..1024+d+15}:
// wc=0 waves accumulate mu_eps cols, wc=1 waves ln_sig cols; 2KB LDS exchange
// pairs them; loss on wc=0 half; one atomicAdd per block.
// grid (64 n, 8 m) = 512 blocks; block 32 rows x (16+16) cols, K=2048 (32 tiles).
__global__ __launch_bounds__(256, 2)
void gemm2loss_k(const bf16_t* __restrict__ A, const float* __restrict__ W,
                 const float* __restrict__ b2, const float* __restrict__ t,
                 const float* __restrict__ x, const float* __restrict__ noise,
                 float* __restrict__ out) {
  __shared__ bf16_t As0[32 * LDK2], As1[32 * LDK2];
  __shared__ bf16_t Bs0[32 * LDK2], Bs1[32 * LDK2];
  __shared__ float lgbuf[32][17];
  __shared__ float red[4];
  int tid = threadIdx.x;
  int lane = tid & 63, wave = tid >> 6;
  int wr = wave & 1, wc = wave >> 1;
  int n0 = blockIdx.x * 16, m0 = blockIdx.y * 32;
  int arow = tid >> 3, akg8 = (tid & 7) * 8;
  int bn = tid & 31, bkg8 = (tid >> 5) * 8;
  int fm = lane & 15, kq = lane >> 4;
  int arr = (wr * 16 + fm) * LDK2 + kq * 8;
  int brr = (wc * 16 + fm) * LDK2 + kq * 8;

  const bf16_t* Ap = A + (size_t)(m0 + arow) * 2048 + akg8;
  // dual-panel column map: bn 0..15 -> me cols n0+bn, bn 16..31 -> lg cols 1024+n0+bn-16
  int bcol = n0 + (bn & 15) + ((bn >> 4) << 10);
  const float* Wp0 = W + (size_t)(bkg8 >> 3) * 8 * 2048 + bcol;

  f32x4 acc = (f32x4)0.0f;   // wc=0: mu_eps frag; wc=1: ln_sig frag
  gemm_loop(Ap, Wp0, As0, As1, Bs0, Bs1, arow, akg8, bn, bkg8, arr, brr,
            32, acc);

  // pair (me, lg) across the wc halves through LDS
  if (wc == 1) {
#pragma unroll
    for (int e = 0; e < 4; ++e)
      lgbuf[wr * 16 + kq * 4 + e][fm] = acc[e];
  }
  __syncthreads();

  float lsum = 0.0f;
  if (wc == 0) {
    int d = n0 + fm;
    float bme = b2[d], blg = b2[1024 + d];
#pragma unroll
    for (int e = 0; e < 4; ++e) {
      int row = m0 + wr * 16 + kq * 4 + e;
      float tv = t[row];
      float om = exp2f(2.0f * tv * L2S);       // 1-gamma
      float gamma = 1.0f - om;
      float rq = sqrtf(om / gamma);
      float w = 1.0f / om;                     // SIGMA1^(-2t)
      bool lowt = tv < 1e-10f;
      float me = acc[e] + bme;
      float lg = lgbuf[wr * 16 + kq * 4 + e][fm] + blg;
      float xs = x[(size_t)row * 1024 + d], ns = noise[(size_t)row * 1024 + d];

      float mu_x = xs + om * ns - rq * me;     // mu/gamma - r*mu_eps
      float sig = rq * __expf(lg);
      if (lowt) { mu_x = 0.f; sig = 1.f; }
      float invs = 0.70710678118654752f / sig; // 1/(sigma*sqrt(2))
      float a = invs * 0.015625f;              // z step per k
      float c0 = (1.f + mu_x) * invs;          // z_k = a*k - c0
      // window |z|<3.5 for the k=1..126 interior sum; saturated tails exact
      float m64 = 64.f * (1.f + mu_x);
      float wdt = 316.78383797157331f * sig;   // 3.5/a = 224*sqrt(2)*sig
      float lo = m64 - wdt, hi = m64 + wdt;
      int klo = (lo < 1.f) ? 1 : ((lo > 126.f) ? 127 : (int)ceilf(lo));
      int khi = (hi < 1.f) ? 0 : ((hi > 126.f) ? 126 : (int)floorf(hi));
      float ss = (float)(126 - khi) - (float)(klo - 1);
      if (khi >= klo) {
        if (a <= 1.0f) {
          // Euler-Maclaurin midpoint: sum ~ (1/a)[G(zb)-G(za)] - (a/(12 sqrt(pi)))(eb-ea)
          float za = fmaf(a, (float)klo - 0.5f, -c0);
          float zb = fmaf(a, (float)khi + 0.5f, -c0);
          const float ISP = 0.56418958354775628f;  // 1/sqrt(pi)
          float ea = __expf(-za * za), eb = __expf(-zb * zb);
          float Ga = fmaf(za, erf_f(za), ISP * ea);
          float Gb = fmaf(zb, erf_f(zb), ISP * eb);
          float S = (Gb - Ga) * __builtin_amdgcn_rcpf(a)
                  - a * 0.047015889f * (eb - ea);  // 1/(12*sqrt(pi))
          ss += S;
        } else {
          for (int k = klo; k <= khi; ++k) ss += erf_f(fmaf(a, (float)k, -c0));
        }
      }
      float z127 = fmaf(a, 127.f, -c0);
      float pO = fmaf(0.48828125f, 1.f + erf_f(z127),
                      fmaf(-0.0078125f, ss, -0.984375f));
      float df = xs - pO;
      lsum += w * df * df;
    }
  }
#pragma unroll
  for (int off = 32; off > 0; off >>= 1) lsum += __shfl_down(lsum, off, 64);
  if ((tid & 63) == 0) red[wave] = lsum;
  __syncthreads();
  if (tid == 0) {
    const float SCALE = 3.9120230054281461f / 262144.0f;  // -ln(0.02)/(B*D)
    atomicAdd(out, (red[0] + red[1] + red[2] + red[3]) * SCALE);
  }
}

extern "C" void kernel_launch(void* const* d_in, const int* in_sizes, int n_in,
                              void* d_out, int out_size, void* d_ws, size_t ws_size,
                              hipStream_t stream) {
  const float* x     = (const float*)d_in[0];
  const float* t     = (const float*)d_in[1];
  const float* noise = (const float*)d_in[2];
  const float* W1    = (const float*)d_in[3];
  const float* b1    = (const float*)d_in[4];
  const float* W2    = (const float*)d_in[5];
  const float* b2    = (const float*)d_in[6];
  float* out = (float*)d_out;

  // ws layout (1.5 MB live): A1 bf16 512 KB, h bf16 1 MB
  char* ws = (char*)d_ws;
  bf16_t* A1 = (bf16_t*)ws;
  bf16_t* h  = (bf16_t*)(ws + 524288);

  prep_k<<<256, 256, 0, stream>>>(x, noise, t, A1, out);
  gemm1h_k<<<dim3(64, 8), 256, 0, stream>>>(A1, W1, b1, t, h);
  gemm2loss_k<<<dim3(64, 8), 256, 0, stream>>>(h, W2, b2, t, x, noise, out);
}